// Round 1
// baseline (963.892 us; speedup 1.0000x reference)
//
#include <hip/hip_runtime.h>

// Problem constants (fixed by reference setup_inputs)
#define BATCH 16
#define HH 64
#define WW 64
#define CC 1024
#define GG 32
#define CG 32          // channels per group
#define TH 8           // tile rows per block
#define TW 16          // tile cols per block
#define EPS 1e-3f
#define ALPHA 0.3f

// LDS: x halo tile 10*18*32 floats = 23 KB, reused for y tile 128*36 floats (18 KB)
#define XS_FLOATS ((TH + 2) * (TW + 2) * CG)   // 5760
#define YS_STRIDE 36                            // padded row stride for y[pixel][c]

__global__ __launch_bounds__(256, 4)
void fused_dw_pw_bn_lrelu(const float* __restrict__ x,
                          const float* __restrict__ dwk,   // (3,3,1,C)
                          const float* __restrict__ pwk,   // (G,Cg,Cg)
                          const float* __restrict__ gamma,
                          const float* __restrict__ beta,
                          const float* __restrict__ mmean,
                          const float* __restrict__ mvar,
                          float* __restrict__ out) {
    __shared__ float smem[XS_FLOATS];

    const int t = threadIdx.x;
    const int tilesW = WW / TW;                 // 4
    const int tile  = blockIdx.x;               // 0..31
    const int tw0   = (tile % tilesW) * TW;
    const int th0   = (tile / tilesW) * TH;
    const int g     = blockIdx.y;               // 0..31
    const int b     = blockIdx.z;               // 0..15
    const int cbase = g * CG;

    // ---------- phase 0: global -> LDS, x halo tile xs[r][col][c] ----------
    // 10*18 pixel positions * 8 float4 each = 1440 float4 loads
    for (int i = t; i < (TH + 2) * (TW + 2) * 8; i += 256) {
        int q   = i & 7;                        // float4 index within 32 channels
        int pp  = i >> 3;                       // halo pixel position 0..179
        int r   = pp / (TW + 2);
        int col = pp % (TW + 2);
        int gh  = th0 - 1 + r;
        int gw  = tw0 - 1 + col;
        float4 v = make_float4(0.f, 0.f, 0.f, 0.f);
        if (gh >= 0 && gh < HH && gw >= 0 && gw < WW) {
            v = *(const float4*)(x + ((size_t)(b * HH + gh) * WW + gw) * CC + cbase + q * 4);
        }
        *(float4*)(smem + (size_t)pp * CG + q * 4) = v;
    }

    // ---------- depthwise taps for this thread's channel quad ----------
    const int c4    = (t & 7) * 4;              // channel quad base within group
    const int pslot = t >> 3;                   // 0..31
    const int pcol  = pslot & 15;               // pixel column 0..15
    const int pr0   = (pslot >> 4) * 4;         // pixel row base: 0 or 4
    float4 k9[9];
    #pragma unroll
    for (int j = 0; j < 9; ++j)
        k9[j] = *(const float4*)(dwk + j * CC + cbase + c4);

    __syncthreads();

    // ---------- phase 1: depthwise conv, column of 4 adjacent rows ----------
    // stream 6 halo rows x 3 cols = 18 LDS reads (vs 36), each feeds up to 3 pixels
    float4 acc[4];
    #pragma unroll
    for (int i = 0; i < 4; ++i) acc[i] = make_float4(0.f, 0.f, 0.f, 0.f);

    #pragma unroll
    for (int xr = 0; xr < 6; ++xr) {
        float4 xq[3];
        #pragma unroll
        for (int dx = 0; dx < 3; ++dx)
            xq[dx] = *(const float4*)(smem + ((pr0 + xr) * (TW + 2) + (pcol + dx)) * CG + c4);
        #pragma unroll
        for (int i = 0; i < 4; ++i) {
            const int dy = xr - i;              // compile-time after unroll
            if (dy >= 0 && dy <= 2) {
                #pragma unroll
                for (int dx = 0; dx < 3; ++dx) {
                    float4 kk = k9[dy * 3 + dx];
                    acc[i].x += xq[dx].x * kk.x;
                    acc[i].y += xq[dx].y * kk.y;
                    acc[i].z += xq[dx].z * kk.z;
                    acc[i].w += xq[dx].w * kk.w;
                }
            }
        }
    }

    __syncthreads();    // all xs reads done; safe to overwrite smem with y

    #pragma unroll
    for (int i = 0; i < 4; ++i) {
        int p = (pr0 + i) * TW + pcol;          // pixel 0..127
        *(float4*)(smem + p * YS_STRIDE + c4) = acc[i];
    }

    // ---------- BN constants for this thread's output-channel quad ----------
    const int d4  = (t & 7) * 4;                // output channel quad 0,4,..,28
    const int ps2 = t >> 3;                     // pixel slot 0..31
    float4 gm = *(const float4*)(gamma + cbase + d4);
    float4 bt = *(const float4*)(beta  + cbase + d4);
    float4 mm = *(const float4*)(mmean + cbase + d4);
    float4 mv = *(const float4*)(mvar  + cbase + d4);
    float4 sc, bi;
    sc.x = gm.x * rsqrtf(mv.x + EPS);  bi.x = bt.x - mm.x * sc.x;
    sc.y = gm.y * rsqrtf(mv.y + EPS);  bi.y = bt.y - mm.y * sc.y;
    sc.z = gm.z * rsqrtf(mv.z + EPS);  bi.z = bt.z - mm.z * sc.z;
    sc.w = gm.w * rsqrtf(mv.w + EPS);  bi.w = bt.w - mm.w * sc.w;

    __syncthreads();    // y tile visible

    // ---------- phase 2: pointwise (4 pixels x 4 out-channels per thread) ----------
    // per cq: 4 weight float4 from global (L1-resident), 4 y float4 from LDS
    float4 o[4];
    #pragma unroll
    for (int i = 0; i < 4; ++i) o[i] = make_float4(0.f, 0.f, 0.f, 0.f);

    const float* wg = pwk + (size_t)g * CG * CG;
    #pragma unroll
    for (int cq = 0; cq < 8; ++cq) {
        float4 w0 = *(const float4*)(wg + (cq * 4 + 0) * CG + d4);
        float4 w1 = *(const float4*)(wg + (cq * 4 + 1) * CG + d4);
        float4 w2 = *(const float4*)(wg + (cq * 4 + 2) * CG + d4);
        float4 w3 = *(const float4*)(wg + (cq * 4 + 3) * CG + d4);
        #pragma unroll
        for (int i = 0; i < 4; ++i) {
            int p = ps2 + i * 32;               // pixel 0..127
            float4 y4 = *(const float4*)(smem + p * YS_STRIDE + cq * 4);
            o[i].x += y4.x * w0.x + y4.y * w1.x + y4.z * w2.x + y4.w * w3.x;
            o[i].y += y4.x * w0.y + y4.y * w1.y + y4.z * w2.y + y4.w * w3.y;
            o[i].z += y4.x * w0.z + y4.y * w1.z + y4.z * w2.z + y4.w * w3.z;
            o[i].w += y4.x * w0.w + y4.y * w1.w + y4.z * w2.w + y4.w * w3.w;
        }
    }

    // ---------- BN + LeakyReLU + coalesced float4 stores ----------
    #pragma unroll
    for (int i = 0; i < 4; ++i) {
        int p  = ps2 + i * 32;
        int pr = p >> 4, pc = p & 15;
        float4 z;
        z.x = o[i].x * sc.x + bi.x;  z.x = (z.x >= 0.f) ? z.x : ALPHA * z.x;
        z.y = o[i].y * sc.y + bi.y;  z.y = (z.y >= 0.f) ? z.y : ALPHA * z.y;
        z.z = o[i].z * sc.z + bi.z;  z.z = (z.z >= 0.f) ? z.z : ALPHA * z.z;
        z.w = o[i].w * sc.w + bi.w;  z.w = (z.w >= 0.f) ? z.w : ALPHA * z.w;
        *(float4*)(out + ((size_t)(b * HH + (th0 + pr)) * WW + (tw0 + pc)) * CC + cbase + d4) = z;
    }
}

extern "C" void kernel_launch(void* const* d_in, const int* in_sizes, int n_in,
                              void* d_out, int out_size, void* d_ws, size_t ws_size,
                              hipStream_t stream) {
    const float* x     = (const float*)d_in[0];
    const float* dwk   = (const float*)d_in[1];
    const float* pwk   = (const float*)d_in[2];
    const float* gamma = (const float*)d_in[3];
    const float* beta  = (const float*)d_in[4];
    const float* mmean = (const float*)d_in[5];
    const float* mvar  = (const float*)d_in[6];
    float* out = (float*)d_out;

    dim3 grid((HH / TH) * (WW / TW), GG, BATCH);  // (32, 32, 16)
    dim3 block(256);
    hipLaunchKernelGGL(fused_dw_pw_bn_lrelu, grid, block, 0, stream,
                       x, dwk, pwk, gamma, beta, mmean, mvar, out);
}